// Round 4
// baseline (293.018 us; speedup 1.0000x reference)
//
#include <hip/hip_runtime.h>
#include <math.h>

// Math reduction (EPS=1e-12 negligible for x ~ N(0,1)):
//   gain = logit x exactly; base = sum_j softplus(x_j);
//   pos = sum_{m=1, x>0} x ; best = max_{m=1} x ; any_pos <=> pos > 0
//   per_sample = base - (pos>0 ? pos : best);  answer = mean over rows.
//
// Structure: ONE 256-thread block per row (grid = 32768). Each thread does
// exactly 2 float4 loads at wave start (row is 250 contiguous float4), ~40
// VALU, a block reduction, and exits. Block turnover keeps the memory system
// fed (copy-kernel-like request flow) instead of relying on software
// pipelining inside long-lived waves, which rounds 1-3 showed the compiler
// defeats (all pinned at 2.6 TB/s).

constexpr int B = 32768;
constexpr int C = 1000;
constexpr int C4 = C / 4;       // 250 float4 per row; threads 250..255 idle
constexpr int THREADS = 256;

__device__ __forceinline__ void elem_update(float x, float m,
                                            float& base, float& pos, float& best) {
    // softplus(x) = max(x,0) + log(1 + exp(-|x|))
    float e  = __expf(-fabsf(x));
    float xp = fmaxf(x, 0.0f);
    base += xp + __logf(1.0f + e);
    pos  += m * xp;                       // m in {0,1}; only x>0 contributes
    if (m != 0.0f) best = fmaxf(best, x);
}

__global__ __launch_bounds__(THREADS)
void row_loss_kernel(const float* __restrict__ X,
                     const float* __restrict__ M,
                     float* __restrict__ partial) {
    const int row = blockIdx.x;
    const int t   = threadIdx.x;

    float base = 0.f, pos = 0.f, best = -INFINITY;

    if (t < C4) {
        const float4* x4 = reinterpret_cast<const float4*>(X + (size_t)row * C);
        const float4* m4 = reinterpret_cast<const float4*>(M + (size_t)row * C);
        float4 x = x4[t];
        float4 m = m4[t];
        elem_update(x.x, m.x, base, pos, best);
        elem_update(x.y, m.y, base, pos, best);
        elem_update(x.z, m.z, base, pos, best);
        elem_update(x.w, m.w, base, pos, best);
    }

    // wave-level reduction (64 lanes)
    #pragma unroll
    for (int off = 32; off > 0; off >>= 1) {
        base += __shfl_down(base, off, 64);
        pos  += __shfl_down(pos,  off, 64);
        best  = fmaxf(best, __shfl_down(best, off, 64));
    }

    __shared__ float sb[4], sp[4], ss[4];
    const int w    = t >> 6;
    const int lane = t & 63;
    if (lane == 0) { sb[w] = base; sp[w] = pos; ss[w] = best; }
    __syncthreads();
    if (t == 0) {
        float b = (sb[0] + sb[1]) + (sb[2] + sb[3]);
        float p = (sp[0] + sp[1]) + (sp[2] + sp[3]);
        float s = fmaxf(fmaxf(ss[0], ss[1]), fmaxf(ss[2], ss[3]));
        partial[row] = b - ((p > 0.f) ? p : s);
    }
}

__global__ __launch_bounds__(256)
void finalize_kernel(const float* __restrict__ partial, float* __restrict__ out) {
    double t = 0.0;
    for (int i = threadIdx.x; i < B; i += 256) t += (double)partial[i];

    #pragma unroll
    for (int off = 32; off > 0; off >>= 1)
        t += __shfl_down(t, off, 64);

    __shared__ double s[4];
    const int lane = threadIdx.x & 63;
    const int w    = threadIdx.x >> 6;
    if (lane == 0) s[w] = t;
    __syncthreads();
    if (threadIdx.x == 0) {
        double r = (s[0] + s[1]) + (s[2] + s[3]);
        out[0] = (float)(r / (double)B);
    }
}

extern "C" void kernel_launch(void* const* d_in, const int* in_sizes, int n_in,
                              void* d_out, int out_size, void* d_ws, size_t ws_size,
                              hipStream_t stream) {
    const float* X  = (const float*)d_in[0];
    const float* M  = (const float*)d_in[1];
    float* out      = (float*)d_out;
    float* partial  = (float*)d_ws;   // B floats = 128 KiB scratch

    row_loss_kernel<<<B, THREADS, 0, stream>>>(X, M, partial);
    finalize_kernel<<<1, 256, 0, stream>>>(partial, out);
}